// Round 16
// baseline (93.663 us; speedup 1.0000x reference)
//
#include <hip/hip_runtime.h>
#include <hip/hip_bf16.h>

typedef __bf16 bf16;
typedef __bf16 v8bf __attribute__((ext_vector_type(8)));
typedef __bf16 v4bf __attribute__((ext_vector_type(4)));
typedef float v4f __attribute__((ext_vector_type(4)));

#define HW 4096
#define CH 256
#define KC 32
#define RD 16
#define NB 2
#define BNEPS 1e-5f
#define LOG2E 1.4426950408889634f

__device__ __forceinline__ float fexp2(float x) {
#if __has_builtin(__builtin_amdgcn_exp2f)
  return __builtin_amdgcn_exp2f(x);
#else
  return exp2f(x);
#endif
}
__device__ __forceinline__ float frcp(float x) {
#if __has_builtin(__builtin_amdgcn_rcpf)
  return __builtin_amdgcn_rcpf(x);
#else
  return 1.f / x;
#endif
}

__device__ __forceinline__ int xcd_swz(int bid, int nwg) {
  return (bid & 7) * (nwg >> 3) + (bid >> 3);
}

// ---------------- workspace byte offsets (~28 MiB) ----------------
#define OFF_QT     0u          // bf16 [2][4096][32] (log2e folded via wall)
#define OFF_KT     524288u     // bf16 [2][4096][32]
#define OFF_BS1    1048576u    // bf16 [2][4096][32] pooled b1 (scaled -log2e*w_gb/9)
#define OFF_BS2    1572864u    // bf16 [2][4096][32] pooled b2
#define OFF_VF     2097152u    // bf16 [2][128 key32][16 ch16][64 lane][8]  V fragments
#define OFF_B1R    6291456u    // bf16 [2][4096][32]
#define OFF_B2R    6815744u    // bf16 [2][4096][32]
#define OFF_PACC   7340032u    // bf16 [1024][32][256] split-K partial ctx (16.8 MB)
#define OFF_PL     24117248u   // f32 [1024*32]
#define OFF_WOBF   24248320u   // bf16 [256][256]
#define OFF_XBT    24379392u   // bf16 [2][4096][256]
#define OFF_WALL   28573696u   // bf16 [2][384][256]
#define OFF_MPART  28966912u   // f32 [2*256][64]

// ---------------- K1: transpose x -> bf16 [n][c] + per-tile channel sums ----------
__global__ __launch_bounds__(256) void k_prep(const float* __restrict__ x,
    bf16* __restrict__ xbt, float* __restrict__ mpart) {
  __shared__ __align__(16) float ts[64][68];
  const int blk = blockIdx.x;               // 512
  const int b  = blk >> 8;
  const int id = blk & 255;
  const int ct = id >> 6, nt = id & 63;
  const int c0 = ct * 64, n0 = nt * 64;
  const int t = threadIdx.x;
  const int crow = t >> 2, nch = (t & 3) * 16;
  const float* xp = x + ((size_t)(b * CH + c0 + crow)) * HW + n0 + nch;
  #pragma unroll
  for (int i = 0; i < 4; ++i)
    *(v4f*)&ts[crow][nch + i * 4] = *(const v4f*)(xp + i * 4);
  __syncthreads();
  {
    float p = 0.f;
    #pragma unroll
    for (int j = 0; j < 16; ++j) p += ts[crow][nch + j];
    p += __shfl_xor(p, 1);
    p += __shfl_xor(p, 2);
    if ((t & 3) == 0) mpart[(size_t)(b * CH + c0 + crow) * 64 + nt] = p;
  }
  const int nl = t >> 2, cc0 = (t & 3) * 16;
  bf16* dst = xbt + ((size_t)(b * HW + n0 + nl)) * CH + c0 + cc0;
  v8bf o0, o1;
  #pragma unroll
  for (int j = 0; j < 8; ++j) { o0[j] = (bf16)ts[cc0 + j][nl]; o1[j] = (bf16)ts[cc0 + 8 + j][nl]; }
  *(v8bf*)dst = o0;
  *(v8bf*)(dst + 8) = o1;
}

// ---------------- K2: pack wall (gate inline) + convert Wo ----------------
__global__ __launch_bounds__(256) void k_pack(
    const float* __restrict__ mpart,
    const float* __restrict__ gw1, const float* __restrict__ gb1,
    const float* __restrict__ gw2, const float* __restrict__ gb2,
    const float* __restrict__ Wq, const float* __restrict__ Wk,
    const float* __restrict__ Wb1, const float* __restrict__ Wb2,
    const float* __restrict__ Wv, const float* __restrict__ Wo,
    bf16* __restrict__ wall, bf16* __restrict__ wo_bf) {
  __shared__ float ms[CH];
  __shared__ float hid[RD];
  const int blk = blockIdx.x;
  const int t = threadIdx.x;
  if (blk >= 768) {                          // Wo f32 -> bf16
    int i = (blk - 768) * 256 + t;
    wo_bf[i] = (bf16)Wo[i];
    return;
  }
  const int b = blk / 384, row = blk % 384;
  float v;
  if (row < 32)       v = Wq[row * CH + t] * LOG2E;
  else if (row < 64) {                       // gate-folded Wk
    float m = 0.f;
    const float* mp = mpart + (size_t)(b * CH + t) * 64;
    #pragma unroll
    for (int j = 0; j < 64; ++j) m += mp[j];
    ms[t] = m * (1.0f / HW);
    __syncthreads();
    if (t < RD) {
      float a = gb1[t];
      for (int c = 0; c < CH; ++c) a += gw1[t * CH + c] * ms[c];
      hid[t] = fmaxf(a, 0.f);
    }
    __syncthreads();
    float a = gb2[t];
    #pragma unroll
    for (int r = 0; r < RD; ++r) a += gw2[t * RD + r] * hid[r];
    float s = 1.f / (1.f + __expf(-a));
    v = Wk[(row - 32) * CH + t] * s;
  }
  else if (row < 96)  v = Wb1[(row - 64) * CH + t];
  else if (row < 128) v = Wb2[(row - 96) * CH + t];
  else                v = Wv[(row - 128) * CH + t];
  wall[((size_t)b * 384 + row) * CH + t] = (bf16)v;
}

// ---------------- K3: fused 1x1 projections via MFMA (single-pass, writes vfrag) ----
__global__ __launch_bounds__(256, 4) void k_proj(
    const bf16* __restrict__ xbt, const bf16* __restrict__ wall,
    bf16* __restrict__ qt, bf16* __restrict__ kt,
    bf16* __restrict__ b1r, bf16* __restrict__ b2r, bf16* __restrict__ vfg) {
  __shared__ __align__(16) bf16 xs[16][264];
  __shared__ __align__(16) bf16 tr[4][16][24];
  const int blk = blockIdx.x;               // 512
  const int b = blk >> 8, nt = blk & 255;
  const int n0 = nt * 16;
  const int t = threadIdx.x;
  {
    const int row = t >> 4, c0 = (t & 15) * 16;
    const bf16* src = xbt + ((size_t)(b * HW + n0 + row)) * CH + c0;
    *(v8bf*)&xs[row][c0] = *(const v8bf*)src;
    *(v8bf*)&xs[row][c0 + 8] = *(const v8bf*)(src + 8);
  }
  __syncthreads();
  const int w = t >> 6, lane = t & 63, cl = lane & 15, kh = lane >> 4;
  const v4f vzero = {0.f, 0.f, 0.f, 0.f};
  v4f acc[6] = {vzero, vzero, vzero, vzero, vzero, vzero};
  const bf16* wb = wall + ((size_t)b * 384 + w * 96) * CH;
  for (int kk = 0; kk < 8; ++kk) {
    v8bf bx = *(const v8bf*)&xs[cl][kk * 32 + kh * 8];
    #pragma unroll
    for (int j = 0; j < 6; ++j) {
      v8bf af = *(const v8bf*)(wb + (size_t)(j * 16 + cl) * CH + kk * 32 + kh * 8);
      acc[j] = __builtin_amdgcn_mfma_f32_16x16x32_bf16(af, bx, acc[j], 0, 0, 0);
    }
  }
  const int n = n0 + cl;
  #pragma unroll
  for (int j = 0; j < 6; ++j) {
    const int o0 = w * 96 + j * 16;
    if (o0 < 128) {
      const bool rel = (o0 >= 64);
      v4bf pk;
      #pragma unroll
      for (int r = 0; r < 4; ++r) {
        float v = acc[j][r];
        if (rel) v = fmaxf(v, 0.f);
        pk[r] = (bf16)v;
      }
      const int seg = o0 >> 5;
      bf16* base = seg == 0 ? qt : seg == 1 ? kt : seg == 2 ? b1r : b2r;
      *(v4bf*)&base[((size_t)b * HW + n) * KC + (o0 & 31) + kh * 4] = pk;
    } else {                                 // v -> fragment-major layout
      #pragma unroll
      for (int r = 0; r < 4; ++r) tr[w][kh * 4 + r][cl] = (bf16)acc[j][r];
      asm volatile("s_waitcnt lgkmcnt(0)" ::: "memory");
      __builtin_amdgcn_sched_barrier(0);
      if (lane < 32) {
        const int clf = lane & 15, khl = (lane >> 4) & 1;
        const int khf = (((n0 >> 4) & 1) << 1) + khl;
        const int s = n0 >> 5, f = (o0 - 128) >> 4;
        v8bf d = *(const v8bf*)&tr[w][clf][khl * 8];
        *(v8bf*)&vfg[((((size_t)b * 128 + s) * 16 + f) * 64 + khf * 16 + clf) * 8] = d;
      }
    }
  }
}

// ---------------- K3b: 1-D 3-tap pool (-log2e*w_gb/9 folded into bs1) ----------------
__global__ __launch_bounds__(256) void k_pool(const bf16* __restrict__ b1r,
    const bf16* __restrict__ b2r, const float* __restrict__ wgb,
    bf16* __restrict__ bs1, bf16* __restrict__ bs2) {
  int i = blockIdx.x * 256 + threadIdx.x;
  int n = (i >> 5) & (HW - 1);
  float a = (float)b1r[i], c = (float)b2r[i];
  if (n > 0)      { a += (float)b1r[i - KC]; c += (float)b2r[i - KC]; }
  if (n < HW - 1) { a += (float)b1r[i + KC]; c += (float)b2r[i + KC]; }
  const float ws = -LOG2E * wgb[0] * (1.f / 9.f);
  bs1[i] = (bf16)(a * ws);
  bs2[i] = (bf16)c;
}

// ---------------- K4: flash attention — 32 rows x 1024 keys, split-4, KVBLK=64 ------
// blk = rt*4 + os; rt = 32-row tile, os = key-split (1024 keys). 16 steps of 64 keys.
// QK: wave w owns key-stripe [w*16,+16) for BOTH row groups. PV: wave w -> all 32
// rows x channels [w*64,+64); V frags direct from global. ONE __syncthreads/step.
// Denominator: per-wave stripe sums reduced ACROSS waves via psh (R15 bugfix).
__global__ __launch_bounds__(256, 4) void k_attn(
    const bf16* __restrict__ qtg, const bf16* __restrict__ ktg,
    const bf16* __restrict__ bs1g, const bf16* __restrict__ bs2g,
    const bf16* __restrict__ vfg,
    bf16* __restrict__ pacc, float* __restrict__ pl) {
  __shared__ __align__(16) bf16 kbuf[2][64][40];   // K dbuf (64-key step)
  __shared__ __align__(16) bf16 bbuf[2][64][40];   // B2 dbuf
  __shared__ __align__(16) bf16 plds[2][32][72];   // P dbuf [qrow32][key64]
  __shared__ __align__(16) bf16 escr[4][16][72];   // epilogue scratch
  __shared__ float psh[4][32];                     // per-wave psum partials
  const int blk = xcd_swz(blockIdx.x, 1024);
  const int rt  = blk >> 2;                  // 0..255
  const int os  = blk & 3;
  const int b   = rt >> 7;
  const int row0 = (rt & 127) * 32;
  const int t = threadIdx.x;
  const int w = t >> 6;
  const int lane = t & 63;
  const int cl = lane & 15, kh = lane >> 4;
  const int kb = os * 1024;
  const v4f vzero = {0.f, 0.f, 0.f, 0.f};
  const bf16* kt = ktg + (size_t)b * HW * KC;
  const bf16* b2 = bs2g + (size_t)b * HW * KC;
  // Q/B1 B-frags for both 16-row groups
  v8bf qf[2], b1f[2];
  #pragma unroll
  for (int rg = 0; rg < 2; ++rg) {
    const size_t qoff = ((size_t)(b * HW + row0 + rg * 16 + cl)) * KC + kh * 8;
    qf[rg]  = *(const v8bf*)(qtg + qoff);
    b1f[rg] = *(const v8bf*)(bs1g + qoff);
  }
  // V fragment base: wave w reads ch-blocks [w*4,+4) of each key32 block
  const bf16* vfb = vfg + ((((size_t)b * 128 + (kb >> 5)) * 16) + w * 4) * 512 + (size_t)lane * 8;
  // K/B2 staging: threads 0-127 -> kbuf, 128-255 -> bbuf; 2 v8bf each (64 rows x 32)
  const int sr = (t >> 1) & 63, sl = (t & 1) * 16;
  const bf16* sbase = (t < 128) ? kt : b2;
  bf16* sd0 = (t < 128) ? &kbuf[0][sr][sl] : &bbuf[0][sr][sl];
  bf16* sd1 = (t < 128) ? &kbuf[1][sr][sl] : &bbuf[1][sr][sl];

  {
    const bf16* sp = sbase + (size_t)(kb + sr) * KC + sl;
    *(v8bf*)sd0 = *(const v8bf*)sp;
    *(v8bf*)(sd0 + 8) = *(const v8bf*)(sp + 8);
  }
  __syncthreads();

  v4f acc[8];                                // [rg][f]: rows rg*16.., ch w*64+f*16..
  #pragma unroll
  for (int f = 0; f < 8; ++f) acc[f] = vzero;
  float psum[2] = {0.f, 0.f};

  for (int s = 0; s < 16; ++s) {
    const int m0 = kb + s * 64;
    const int pb = s & 1;
    // next K/B2 prefetch (2 v8bf)
    v8bf pr0, pr1;
    if (s < 15) {
      const bf16* sp = sbase + (size_t)(m0 + 64 + sr) * KC + sl;
      pr0 = *(const v8bf*)sp;
      pr1 = *(const v8bf*)(sp + 8);
    }
    // swapped QK: wave w -> keys [w*16,+16); C[key][qrow] lane-local per row
    #pragma unroll
    for (int rg = 0; rg < 2; ++rg) {
      v8bf kf  = *(const v8bf*)&kbuf[pb][w * 16 + cl][kh * 8];
      v8bf b2f = *(const v8bf*)&bbuf[pb][w * 16 + cl][kh * 8];
      v4f sim = __builtin_amdgcn_mfma_f32_16x16x32_bf16(kf,  qf[rg],  vzero, 0, 0, 0);
      v4f bia = __builtin_amdgcn_mfma_f32_16x16x32_bf16(b2f, b1f[rg], vzero, 0, 0, 0);
      v4bf pk;
      #pragma unroll
      for (int r = 0; r < 4; ++r) {
        float bm = frcp(1.f + fexp2(bia[r]));   // sigmoid (-log2e folded in bs1)
        float pv = fexp2(sim[r] * bm);          // exp (log2e folded in qt)
        psum[rg] += pv;
        pk[r] = (bf16)pv;
      }
      // P[qrow = rg*16+cl][key = w*16 + kh*4 + r]
      *(v4bf*)&plds[pb][rg * 16 + cl][w * 16 + kh * 4] = pk;
    }
    // stage next K/B2 into the other buffer
    if (s < 15) {
      bf16* sd = pb ? sd0 : sd1;
      *(v8bf*)sd = pr0;
      *(v8bf*)(sd + 8) = pr1;
    }
    __syncthreads();                            // ONE barrier: P[pb], K[pb^1]
    // PV: V B-frags direct from global (coalesced 1KB/instr, L2-resident)
    const bf16* vs = vfb + (size_t)(s * 2) * 8192;
    v8bf vf[2][4];
    #pragma unroll
    for (int ks = 0; ks < 2; ++ks)
      #pragma unroll
      for (int f = 0; f < 4; ++f)
        vf[ks][f] = *(const v8bf*)(vs + (size_t)ks * 8192 + f * 512);
    #pragma unroll
    for (int rg = 0; rg < 2; ++rg)
      #pragma unroll
      for (int ks = 0; ks < 2; ++ks) {
        v8bf pa = *(const v8bf*)&plds[pb][rg * 16 + cl][ks * 32 + kh * 8];
        #pragma unroll
        for (int f = 0; f < 4; ++f)
          acc[rg * 4 + f] = __builtin_amdgcn_mfma_f32_16x16x32_bf16(pa, vf[ks][f], acc[rg * 4 + f], 0, 0, 0);
      }
  }
  __syncthreads();

  // ---- epilogue ----
  // denominator: wave-stripe partials (16 keys/wave) must be summed ACROSS waves.
  #pragma unroll
  for (int rg = 0; rg < 2; ++rg) {
    float s2 = psum[rg];
    s2 += __shfl_xor(s2, 16);
    s2 += __shfl_xor(s2, 32);
    if (kh == 0) psh[w][rg * 16 + cl] = s2;     // per-wave partial for its key stripe
  }
  __syncthreads();
  if (t < 32)
    pl[blk * 32 + t] = psh[0][t] + psh[1][t] + psh[2][t] + psh[3][t];
  bf16* po = pacc + (size_t)blk * 32 * CH;
  for (int rg = 0; rg < 2; ++rg) {
    #pragma unroll
    for (int f = 0; f < 4; ++f)
      #pragma unroll
      for (int r = 0; r < 4; ++r)
        escr[w][kh * 4 + r][f * 16 + cl] = (bf16)acc[rg * 4 + f][r];
    asm volatile("s_waitcnt lgkmcnt(0)" ::: "memory");
    __builtin_amdgcn_sched_barrier(0);
    #pragma unroll
    for (int it = 0; it < 2; ++it) {
      int row = lane >> 2, chunk = it * 4 + (lane & 3);
      v8bf d = *(const v8bf*)&escr[w][row][chunk * 8];
      *(v8bf*)&po[(size_t)(rg * 16 + row) * CH + w * 64 + chunk * 8] = d;
    }
  }
}

// ---------------- K5: fused combine (coalesced) + 1x1 conv + BN + ReLU + residual ---
__global__ __launch_bounds__(256) void k_outc(
    const bf16* __restrict__ pacc, const float* __restrict__ pl,
    const bf16* __restrict__ wo,
    const float* __restrict__ bns, const float* __restrict__ bnb,
    const float* __restrict__ bnm, const float* __restrict__ bnv,
    const float* __restrict__ gamma, const float* __restrict__ x,
    float* __restrict__ out) {
  __shared__ __align__(16) bf16 cs[16][264];
  const int blk = xcd_swz(blockIdx.x, 512);
  const int n0g = blk * 16;
  const int b   = n0g >> 12;
  const int n0  = n0g & (HW - 1);
  const int t = threadIdx.x;
  const int base = (blk >> 1) * 4;             // rt*4 splits
  {
    const int r16 = t >> 4;
    const int ch0 = (t & 15) * 16;
    const int rl = (blk & 1) * 16 + r16;       // row within 32-row tile
    float den = 0.f;
    #pragma unroll
    for (int s = 0; s < 4; ++s) den += pl[(base + s) * 32 + rl];
    const float inv = 1.f / den;
    float sum[16];
    #pragma unroll
    for (int j = 0; j < 16; ++j) sum[j] = 0.f;
    #pragma unroll
    for (int s = 0; s < 4; ++s) {
      const bf16* pp = &pacc[((size_t)(base + s) * 32 + rl) * CH + ch0];
      v8bf p0 = *(const v8bf*)pp;
      v8bf p1 = *(const v8bf*)(pp + 8);
      #pragma unroll
      for (int j = 0; j < 8; ++j) { sum[j] += (float)p0[j]; sum[8 + j] += (float)p1[j]; }
    }
    v8bf o0, o1;
    #pragma unroll
    for (int j = 0; j < 8; ++j) {
      o0[j] = (bf16)(sum[j] * inv);
      o1[j] = (bf16)(sum[8 + j] * inv);
    }
    *(v8bf*)&cs[r16][ch0] = o0;
    *(v8bf*)&cs[r16][ch0 + 8] = o1;
  }
  __syncthreads();
  const int w = t >> 6, lane = t & 63, cl = lane & 15, kh = lane >> 4;
  const v4f vzero = {0.f, 0.f, 0.f, 0.f};
  v8bf a[8];
  #pragma unroll
  for (int kk = 0; kk < 8; ++kk)
    a[kk] = *(const v8bf*)&cs[cl][kk * 32 + kh * 8];
  v4f acc[4] = {vzero, vzero, vzero, vzero};
  #pragma unroll
  for (int kk = 0; kk < 8; ++kk)
    #pragma unroll
    for (int cg = 0; cg < 4; ++cg) {
      v8bf bfr = *(const v8bf*)(wo + (size_t)(w * 64 + cg * 16 + cl) * CH + kk * 32 + kh * 8);
      acc[cg] = __builtin_amdgcn_mfma_f32_16x16x32_bf16(a[kk], bfr, acc[cg], 0, 0, 0);
    }
  const float g = gamma[0];
  #pragma unroll
  for (int cg = 0; cg < 4; ++cg) {
    int o = w * 64 + cg * 16 + cl;
    float isc = bns[o] / sqrtf(bnv[o] + BNEPS);
    float mu = bnm[o], bb = bnb[o];
    size_t oi = ((size_t)b * CH + o) * HW + n0 + kh * 4;
    v4f xv = *(const v4f*)&x[oi];
    v4f ov;
    #pragma unroll
    for (int r = 0; r < 4; ++r) {
      float v = (acc[cg][r] - mu) * isc + bb;
      v = fmaxf(v, 0.f);
      ov[r] = g * v + xv[r];
    }
    *(v4f*)&out[oi] = ov;
  }
}

// ---------------- launch ----------------
extern "C" void kernel_launch(void* const* d_in, const int* in_sizes, int n_in,
                              void* d_out, int out_size, void* d_ws, size_t ws_size,
                              hipStream_t stream) {
  const float* x    = (const float*)d_in[0];
  const float* Wq   = (const float*)d_in[1];
  const float* Wk   = (const float*)d_in[2];
  const float* Wv   = (const float*)d_in[3];
  const float* Wb1  = (const float*)d_in[4];
  const float* Wb2  = (const float*)d_in[5];
  const float* wgb  = (const float*)d_in[6];
  const float* gw1  = (const float*)d_in[7];
  const float* gb1  = (const float*)d_in[8];
  const float* gw2  = (const float*)d_in[9];
  const float* gb2  = (const float*)d_in[10];
  const float* Wo   = (const float*)d_in[11];
  const float* bns  = (const float*)d_in[12];
  const float* bnb  = (const float*)d_in[13];
  const float* bnm  = (const float*)d_in[14];
  const float* bnv  = (const float*)d_in[15];
  const float* gam  = (const float*)d_in[16];

  char* ws = (char*)d_ws;
  bf16* qt    = (bf16*)(ws + OFF_QT);
  bf16* kt    = (bf16*)(ws + OFF_KT);
  bf16* bs1   = (bf16*)(ws + OFF_BS1);
  bf16* bs2   = (bf16*)(ws + OFF_BS2);
  bf16* vfg   = (bf16*)(ws + OFF_VF);
  bf16* b1r   = (bf16*)(ws + OFF_B1R);
  bf16* b2r   = (bf16*)(ws + OFF_B2R);
  bf16* pacc  = (bf16*)(ws + OFF_PACC);
  float* plv  = (float*)(ws + OFF_PL);
  bf16* wobf  = (bf16*)(ws + OFF_WOBF);
  bf16* xbt   = (bf16*)(ws + OFF_XBT);
  bf16* wall  = (bf16*)(ws + OFF_WALL);
  float* mprt = (float*)(ws + OFF_MPART);
  float* out  = (float*)d_out;

  hipLaunchKernelGGL(k_prep, dim3(512),  dim3(256), 0, stream, x, xbt, mprt);
  hipLaunchKernelGGL(k_pack, dim3(1024), dim3(256), 0, stream, mprt, gw1, gb1, gw2, gb2,
                     Wq, Wk, Wb1, Wb2, Wv, Wo, wall, wobf);
  hipLaunchKernelGGL(k_proj, dim3(512),  dim3(256), 0, stream, xbt, wall, qt, kt, b1r, b2r, vfg);
  hipLaunchKernelGGL(k_pool, dim3(NB * HW * KC / 256), dim3(256), 0, stream, b1r, b2r, wgb, bs1, bs2);
  hipLaunchKernelGGL(k_attn, dim3(1024), dim3(256), 0, stream, qt, kt, bs1, bs2, vfg, pacc, plv);
  hipLaunchKernelGGL(k_outc, dim3(512),  dim3(256), 0, stream, pacc, plv, wobf, bns, bnb, bnm, bnv, gam, x, out);
}

// Round 17
// 79.356 us; speedup vs baseline: 1.1803x; 1.1803x over previous
//
#include <hip/hip_runtime.h>
#include <hip/hip_bf16.h>

typedef __bf16 bf16;
typedef __bf16 v8bf __attribute__((ext_vector_type(8)));
typedef __bf16 v4bf __attribute__((ext_vector_type(4)));
typedef float v4f __attribute__((ext_vector_type(4)));

#define HW 4096
#define CH 256
#define KC 32
#define RD 16
#define NB 2
#define BNEPS 1e-5f
#define LOG2E 1.4426950408889634f

__device__ __forceinline__ float fexp2(float x) {
#if __has_builtin(__builtin_amdgcn_exp2f)
  return __builtin_amdgcn_exp2f(x);
#else
  return exp2f(x);
#endif
}
__device__ __forceinline__ float frcp(float x) {
#if __has_builtin(__builtin_amdgcn_rcpf)
  return __builtin_amdgcn_rcpf(x);
#else
  return 1.f / x;
#endif
}

__device__ __forceinline__ int xcd_swz(int bid, int nwg) {
  return (bid & 7) * (nwg >> 3) + (bid >> 3);
}

// ---------------- workspace byte offsets (~44 MiB) ----------------
#define OFF_QT     0u          // bf16 [2][4096][32] (log2e folded via wall)
#define OFF_KT     524288u     // bf16 [2][4096][32]
#define OFF_BS1    1048576u    // bf16 [2][4096][32] pooled b1 (scaled -log2e*w_gb/9)
#define OFF_BS2    1572864u    // bf16 [2][4096][32] pooled b2
#define OFF_VF     2097152u    // bf16 [2][128 key32][16 ch16][64 lane][8]  V fragments
#define OFF_B1R    6291456u    // bf16 [2][4096][32]
#define OFF_B2R    6815744u    // bf16 [2][4096][32]
#define OFF_PACC   7340032u    // bf16 [1024][64][256] split-K partial ctx
#define OFF_PL     40894464u   // f32 [1024*64]
#define OFF_WOBF   41156608u   // bf16 [256][256]
#define OFF_XBT    41287680u   // bf16 [2][4096][256]
#define OFF_WALL   45481984u   // bf16 [2][384][256]
#define OFF_MPART  45875200u   // f32 [2*256][64]

// ---------------- K1: transpose x -> bf16 [n][c] + per-tile channel sums ----------
__global__ __launch_bounds__(256) void k_prep(const float* __restrict__ x,
    bf16* __restrict__ xbt, float* __restrict__ mpart) {
  __shared__ __align__(16) float ts[64][68];
  const int blk = blockIdx.x;               // 512
  const int b  = blk >> 8;
  const int id = blk & 255;
  const int ct = id >> 6, nt = id & 63;
  const int c0 = ct * 64, n0 = nt * 64;
  const int t = threadIdx.x;
  const int crow = t >> 2, nch = (t & 3) * 16;
  const float* xp = x + ((size_t)(b * CH + c0 + crow)) * HW + n0 + nch;
  #pragma unroll
  for (int i = 0; i < 4; ++i)
    *(v4f*)&ts[crow][nch + i * 4] = *(const v4f*)(xp + i * 4);
  __syncthreads();
  {
    float p = 0.f;
    #pragma unroll
    for (int j = 0; j < 16; ++j) p += ts[crow][nch + j];
    p += __shfl_xor(p, 1);
    p += __shfl_xor(p, 2);
    if ((t & 3) == 0) mpart[(size_t)(b * CH + c0 + crow) * 64 + nt] = p;
  }
  const int nl = t >> 2, cc0 = (t & 3) * 16;
  bf16* dst = xbt + ((size_t)(b * HW + n0 + nl)) * CH + c0 + cc0;
  v8bf o0, o1;
  #pragma unroll
  for (int j = 0; j < 8; ++j) { o0[j] = (bf16)ts[cc0 + j][nl]; o1[j] = (bf16)ts[cc0 + 8 + j][nl]; }
  *(v8bf*)dst = o0;
  *(v8bf*)(dst + 8) = o1;
}

// ---------------- K2: pack wall (gate inline) + convert Wo ----------------
__global__ __launch_bounds__(256) void k_pack(
    const float* __restrict__ mpart,
    const float* __restrict__ gw1, const float* __restrict__ gb1,
    const float* __restrict__ gw2, const float* __restrict__ gb2,
    const float* __restrict__ Wq, const float* __restrict__ Wk,
    const float* __restrict__ Wb1, const float* __restrict__ Wb2,
    const float* __restrict__ Wv, const float* __restrict__ Wo,
    bf16* __restrict__ wall, bf16* __restrict__ wo_bf) {
  __shared__ float ms[CH];
  __shared__ float hid[RD];
  const int blk = blockIdx.x;
  const int t = threadIdx.x;
  if (blk >= 768) {                          // Wo f32 -> bf16
    int i = (blk - 768) * 256 + t;
    wo_bf[i] = (bf16)Wo[i];
    return;
  }
  const int b = blk / 384, row = blk % 384;
  float v;
  if (row < 32)       v = Wq[row * CH + t] * LOG2E;
  else if (row < 64) {                       // gate-folded Wk
    float m = 0.f;
    const float* mp = mpart + (size_t)(b * CH + t) * 64;
    #pragma unroll
    for (int j = 0; j < 64; ++j) m += mp[j];
    ms[t] = m * (1.0f / HW);
    __syncthreads();
    if (t < RD) {
      float a = gb1[t];
      for (int c = 0; c < CH; ++c) a += gw1[t * CH + c] * ms[c];
      hid[t] = fmaxf(a, 0.f);
    }
    __syncthreads();
    float a = gb2[t];
    #pragma unroll
    for (int r = 0; r < RD; ++r) a += gw2[t * RD + r] * hid[r];
    float s = 1.f / (1.f + __expf(-a));
    v = Wk[(row - 32) * CH + t] * s;
  }
  else if (row < 96)  v = Wb1[(row - 64) * CH + t];
  else if (row < 128) v = Wb2[(row - 96) * CH + t];
  else                v = Wv[(row - 128) * CH + t];
  wall[((size_t)b * 384 + row) * CH + t] = (bf16)v;
}

// ---------------- K3: fused 1x1 projections via MFMA (single-pass, writes vfrag) ----
// blk = b*256 + nt16; block computes ALL 384 outputs for a 16-n tile.
__global__ __launch_bounds__(256, 4) void k_proj(
    const bf16* __restrict__ xbt, const bf16* __restrict__ wall,
    bf16* __restrict__ qt, bf16* __restrict__ kt,
    bf16* __restrict__ b1r, bf16* __restrict__ b2r, bf16* __restrict__ vfg) {
  __shared__ __align__(16) bf16 xs[16][264];
  __shared__ __align__(16) bf16 tr[4][16][24];
  const int blk = blockIdx.x;               // 512
  const int b = blk >> 8, nt = blk & 255;
  const int n0 = nt * 16;
  const int t = threadIdx.x;
  {
    const int row = t >> 4, c0 = (t & 15) * 16;
    const bf16* src = xbt + ((size_t)(b * HW + n0 + row)) * CH + c0;
    *(v8bf*)&xs[row][c0] = *(const v8bf*)src;
    *(v8bf*)&xs[row][c0 + 8] = *(const v8bf*)(src + 8);
  }
  __syncthreads();
  const int w = t >> 6, lane = t & 63, cl = lane & 15, kh = lane >> 4;
  const v4f vzero = {0.f, 0.f, 0.f, 0.f};
  v4f acc[6] = {vzero, vzero, vzero, vzero, vzero, vzero};
  const bf16* wb = wall + ((size_t)b * 384 + w * 96) * CH;
  for (int kk = 0; kk < 8; ++kk) {
    v8bf bx = *(const v8bf*)&xs[cl][kk * 32 + kh * 8];
    #pragma unroll
    for (int j = 0; j < 6; ++j) {
      v8bf af = *(const v8bf*)(wb + (size_t)(j * 16 + cl) * CH + kk * 32 + kh * 8);
      acc[j] = __builtin_amdgcn_mfma_f32_16x16x32_bf16(af, bx, acc[j], 0, 0, 0);
    }
  }
  const int n = n0 + cl;
  #pragma unroll
  for (int j = 0; j < 6; ++j) {
    const int o0 = w * 96 + j * 16;
    if (o0 < 128) {
      const bool rel = (o0 >= 64);
      v4bf pk;
      #pragma unroll
      for (int r = 0; r < 4; ++r) {
        float v = acc[j][r];
        if (rel) v = fmaxf(v, 0.f);
        pk[r] = (bf16)v;
      }
      const int seg = o0 >> 5;
      bf16* base = seg == 0 ? qt : seg == 1 ? kt : seg == 2 ? b1r : b2r;
      *(v4bf*)&base[((size_t)b * HW + n) * KC + (o0 & 31) + kh * 4] = pk;
    } else {                                 // v -> fragment-major layout
      #pragma unroll
      for (int r = 0; r < 4; ++r) tr[w][kh * 4 + r][cl] = (bf16)acc[j][r];
      asm volatile("s_waitcnt lgkmcnt(0)" ::: "memory");
      __builtin_amdgcn_sched_barrier(0);
      if (lane < 32) {
        const int clf = lane & 15, khl = (lane >> 4) & 1;
        const int khf = (((n0 >> 4) & 1) << 1) + khl;   // n-half within key32 block
        const int s = n0 >> 5, f = (o0 - 128) >> 4;
        v8bf d = *(const v8bf*)&tr[w][clf][khl * 8];
        *(v8bf*)&vfg[((((size_t)b * 128 + s) * 16 + f) * 64 + khf * 16 + clf) * 8] = d;
      }
    }
  }
}

// ---------------- K3b: 1-D 3-tap pool (-log2e*w_gb/9 folded into bs1) ----------------
__global__ __launch_bounds__(256) void k_pool(const bf16* __restrict__ b1r,
    const bf16* __restrict__ b2r, const float* __restrict__ wgb,
    bf16* __restrict__ bs1, bf16* __restrict__ bs2) {
  int i = blockIdx.x * 256 + threadIdx.x;
  int n = (i >> 5) & (HW - 1);
  float a = (float)b1r[i], c = (float)b2r[i];
  if (n > 0)      { a += (float)b1r[i - KC]; c += (float)b2r[i - KC]; }
  if (n < HW - 1) { a += (float)b1r[i + KC]; c += (float)b2r[i + KC]; }
  const float ws = -LOG2E * wgb[0] * (1.f / 9.f);
  bs1[i] = (bf16)(a * ws);
  bs2[i] = (bf16)c;
}

// ---------------- K4: flash attention — R14 proven structure + setprio(T5) ----------
// blk = rt*8 + os; 64-row tile, 512-key split, 16 steps of 32 keys.
// QK: wave w -> P rows [w*16,+16) (swapped MFMA, lane-local).
// PV: wave w -> all 64 rows x channels [w*64,+64); V B-frags read directly from
// fragment-major global vfrag (L2-resident, 1KB coalesced per wave-instr).
// plds/kbuf/bbuf double-buffered, ONE __syncthreads per step (R11-proven scheme).
__global__ __launch_bounds__(256, 4) void k_attn(
    const bf16* __restrict__ qtg, const bf16* __restrict__ ktg,
    const bf16* __restrict__ bs1g, const bf16* __restrict__ bs2g,
    const bf16* __restrict__ vfg,
    bf16* __restrict__ pacc, float* __restrict__ pl) {
  __shared__ __align__(16) bf16 kbuf[2][32][40];   // K dbuf
  __shared__ __align__(16) bf16 bbuf[2][32][40];   // B2 dbuf
  __shared__ __align__(16) bf16 plds[2][64][40];   // P dbuf [qrow][key]
  __shared__ __align__(16) bf16 escr[4][16][72];   // epilogue scratch
  const int blk = xcd_swz(blockIdx.x, 1024);
  const int rt  = blk >> 3;
  const int os  = blk & 7;
  const int b   = rt >> 6;
  const int row0 = (rt & 63) * 64;
  const int t = threadIdx.x;
  const int w = t >> 6;
  const int lane = t & 63;
  const int cl = lane & 15, kh = lane >> 4;
  const int kb = os * 512;
  const v4f vzero = {0.f, 0.f, 0.f, 0.f};
  const size_t qoff = ((size_t)(b * HW + row0 + w * 16 + cl)) * KC + kh * 8;
  const v8bf qf  = *(const v8bf*)(qtg + qoff);
  const v8bf b1f = *(const v8bf*)(bs1g + qoff);
  const bf16* kt = ktg + (size_t)b * HW * KC;
  const bf16* b2 = bs2g + (size_t)b * HW * KC;
  // V fragment base: wave w reads ch-blocks [w*4, +4) of each key32 block
  const bf16* vfb = vfg + ((((size_t)b * 128 + (kb >> 5)) * 16) + w * 4) * 512 + (size_t)lane * 8;
  // K/B2 staging: threads 0-127 -> kbuf, 128-255 -> bbuf (1 v8bf each)
  const int sr = (t >> 2) & 31, sl = (t & 3) * 8;
  const bf16* sbase = (t < 128) ? kt : b2;
  bf16* sd0 = (t < 128) ? &kbuf[0][sr][sl] : &bbuf[0][sr][sl];
  bf16* sd1 = (t < 128) ? &kbuf[1][sr][sl] : &bbuf[1][sr][sl];

  *(v8bf*)sd0 = *(const v8bf*)(sbase + (size_t)(kb + sr) * KC + sl);
  __syncthreads();

  v4f acc[16];
  #pragma unroll
  for (int f = 0; f < 16; ++f) acc[f] = vzero;
  float psum = 0.f;

  for (int s = 0; s < 16; ++s) {
    const int m0 = kb + s * 32;
    const int pb = s & 1;
    // next K/B2 prefetch
    v8bf pr;
    if (s < 15)
      pr = *(const v8bf*)(sbase + (size_t)(m0 + 32 + sr) * KC + sl);
    // swapped QK from kbuf[pb]: lane owns 8 keys of its own row (w*16+cl)
    #pragma unroll
    for (int cb = 0; cb < 2; ++cb) {
      v8bf kf  = *(const v8bf*)&kbuf[pb][cb * 16 + cl][kh * 8];
      v8bf b2f = *(const v8bf*)&bbuf[pb][cb * 16 + cl][kh * 8];
      v4f sim = __builtin_amdgcn_mfma_f32_16x16x32_bf16(kf,  qf,  vzero, 0, 0, 0);
      v4f bia = __builtin_amdgcn_mfma_f32_16x16x32_bf16(b2f, b1f, vzero, 0, 0, 0);
      v4bf pk;
      #pragma unroll
      for (int r = 0; r < 4; ++r) {
        float bm = frcp(1.f + fexp2(bia[r]));   // sigmoid (-log2e folded in bs1)
        float pv = fexp2(sim[r] * bm);          // exp (log2e folded in qt)
        psum += pv;
        pk[r] = (bf16)pv;
      }
      *(v4bf*)&plds[pb][w * 16 + cl][cb * 16 + kh * 4] = pk;
    }
    // stage next K/B2 into the other buffer (pr consumed before barrier -> drain free)
    if (s < 15) {
      bf16* sd = pb ? sd0 : sd1;
      *(v8bf*)sd = pr;
    }
    __syncthreads();                            // ONE barrier: P[pb], K[pb^1]
    // PV: V B-frags direct from global (coalesced 1KB/instr, L2-resident)
    const bf16* vs = vfb + (size_t)s * 8192;
    v8bf vf0 = *(const v8bf*)(vs);
    v8bf vf1 = *(const v8bf*)(vs + 512);
    v8bf vf2 = *(const v8bf*)(vs + 1024);
    v8bf vf3 = *(const v8bf*)(vs + 1536);
    __builtin_amdgcn_s_setprio(1);              // T5: favor MFMA cluster
    #pragma unroll
    for (int rg = 0; rg < 4; ++rg) {
      v8bf pa = *(const v8bf*)&plds[pb][rg * 16 + cl][kh * 8];
      acc[rg * 4 + 0] = __builtin_amdgcn_mfma_f32_16x16x32_bf16(pa, vf0, acc[rg * 4 + 0], 0, 0, 0);
      acc[rg * 4 + 1] = __builtin_amdgcn_mfma_f32_16x16x32_bf16(pa, vf1, acc[rg * 4 + 1], 0, 0, 0);
      acc[rg * 4 + 2] = __builtin_amdgcn_mfma_f32_16x16x32_bf16(pa, vf2, acc[rg * 4 + 2], 0, 0, 0);
      acc[rg * 4 + 3] = __builtin_amdgcn_mfma_f32_16x16x32_bf16(pa, vf3, acc[rg * 4 + 3], 0, 0, 0);
    }
    __builtin_amdgcn_s_setprio(0);
  }
  __syncthreads();

  // ---- epilogue ----
  {
    float s2 = psum;
    s2 += __shfl_xor(s2, 16);
    s2 += __shfl_xor(s2, 32);
    if (kh == 0) pl[blk * 64 + w * 16 + cl] = s2;
  }
  bf16* po = pacc + (size_t)blk * 64 * CH;
  for (int rg = 0; rg < 4; ++rg) {
    #pragma unroll
    for (int f = 0; f < 4; ++f)
      #pragma unroll
      for (int r = 0; r < 4; ++r)
        escr[w][kh * 4 + r][f * 16 + cl] = (bf16)acc[rg * 4 + f][r];
    asm volatile("s_waitcnt lgkmcnt(0)" ::: "memory");
    __builtin_amdgcn_sched_barrier(0);
    #pragma unroll
    for (int it = 0; it < 2; ++it) {
      int row = lane >> 2, chunk = it * 4 + (lane & 3);
      v8bf d = *(const v8bf*)&escr[w][row][chunk * 8];
      *(v8bf*)&po[(size_t)(rg * 16 + row) * CH + w * 64 + chunk * 8] = d;
    }
  }
}

// ---------------- K5: fused combine (coalesced) + 1x1 conv + BN + ReLU + residual ---
__global__ __launch_bounds__(256) void k_outc(
    const bf16* __restrict__ pacc, const float* __restrict__ pl,
    const bf16* __restrict__ wo,
    const float* __restrict__ bns, const float* __restrict__ bnb,
    const float* __restrict__ bnm, const float* __restrict__ bnv,
    const float* __restrict__ gamma, const float* __restrict__ x,
    float* __restrict__ out) {
  __shared__ __align__(16) bf16 cs[16][264];
  const int blk = xcd_swz(blockIdx.x, 512);
  const int n0g = blk * 16;
  const int b   = n0g >> 12;
  const int n0  = n0g & (HW - 1);
  const int t = threadIdx.x;
  const int base = (blk >> 2) * 8;
  {
    const int r16 = t >> 4;
    const int ch0 = (t & 15) * 16;
    const int rl = (blk & 3) * 16 + r16;
    float den = 0.f;
    #pragma unroll
    for (int s = 0; s < 8; ++s) den += pl[(base + s) * 64 + rl];
    const float inv = 1.f / den;
    float sum[16];
    #pragma unroll
    for (int j = 0; j < 16; ++j) sum[j] = 0.f;
    #pragma unroll
    for (int s = 0; s < 8; ++s) {
      const bf16* pp = &pacc[((size_t)(base + s) * 64 + rl) * CH + ch0];
      v8bf p0 = *(const v8bf*)pp;
      v8bf p1 = *(const v8bf*)(pp + 8);
      #pragma unroll
      for (int j = 0; j < 8; ++j) { sum[j] += (float)p0[j]; sum[8 + j] += (float)p1[j]; }
    }
    v8bf o0, o1;
    #pragma unroll
    for (int j = 0; j < 8; ++j) {
      o0[j] = (bf16)(sum[j] * inv);
      o1[j] = (bf16)(sum[8 + j] * inv);
    }
    *(v8bf*)&cs[r16][ch0] = o0;
    *(v8bf*)&cs[r16][ch0 + 8] = o1;
  }
  __syncthreads();
  const int w = t >> 6, lane = t & 63, cl = lane & 15, kh = lane >> 4;
  const v4f vzero = {0.f, 0.f, 0.f, 0.f};
  v8bf a[8];
  #pragma unroll
  for (int kk = 0; kk < 8; ++kk)
    a[kk] = *(const v8bf*)&cs[cl][kk * 32 + kh * 8];
  v4f acc[4] = {vzero, vzero, vzero, vzero};
  #pragma unroll
  for (int kk = 0; kk < 8; ++kk)
    #pragma unroll
    for (int cg = 0; cg < 4; ++cg) {
      v8bf bfr = *(const v8bf*)(wo + (size_t)(w * 64 + cg * 16 + cl) * CH + kk * 32 + kh * 8);
      acc[cg] = __builtin_amdgcn_mfma_f32_16x16x32_bf16(a[kk], bfr, acc[cg], 0, 0, 0);
    }
  const float g = gamma[0];
  #pragma unroll
  for (int cg = 0; cg < 4; ++cg) {
    int o = w * 64 + cg * 16 + cl;
    float isc = bns[o] / sqrtf(bnv[o] + BNEPS);
    float mu = bnm[o], bb = bnb[o];
    size_t oi = ((size_t)b * CH + o) * HW + n0 + kh * 4;
    v4f xv = *(const v4f*)&x[oi];
    v4f ov;
    #pragma unroll
    for (int r = 0; r < 4; ++r) {
      float v = (acc[cg][r] - mu) * isc + bb;
      v = fmaxf(v, 0.f);
      ov[r] = g * v + xv[r];
    }
    *(v4f*)&out[oi] = ov;
  }
}

// ---------------- launch ----------------
extern "C" void kernel_launch(void* const* d_in, const int* in_sizes, int n_in,
                              void* d_out, int out_size, void* d_ws, size_t ws_size,
                              hipStream_t stream) {
  const float* x    = (const float*)d_in[0];
  const float* Wq   = (const float*)d_in[1];
  const float* Wk   = (const float*)d_in[2];
  const float* Wv   = (const float*)d_in[3];
  const float* Wb1  = (const float*)d_in[4];
  const float* Wb2  = (const float*)d_in[5];
  const float* wgb  = (const float*)d_in[6];
  const float* gw1  = (const float*)d_in[7];
  const float* gb1  = (const float*)d_in[8];
  const float* gw2  = (const float*)d_in[9];
  const float* gb2  = (const float*)d_in[10];
  const float* Wo   = (const float*)d_in[11];
  const float* bns  = (const float*)d_in[12];
  const float* bnb  = (const float*)d_in[13];
  const float* bnm  = (const float*)d_in[14];
  const float* bnv  = (const float*)d_in[15];
  const float* gam  = (const float*)d_in[16];

  char* ws = (char*)d_ws;
  bf16* qt    = (bf16*)(ws + OFF_QT);
  bf16* kt    = (bf16*)(ws + OFF_KT);
  bf16* bs1   = (bf16*)(ws + OFF_BS1);
  bf16* bs2   = (bf16*)(ws + OFF_BS2);
  bf16* vfg   = (bf16*)(ws + OFF_VF);
  bf16* b1r   = (bf16*)(ws + OFF_B1R);
  bf16* b2r   = (bf16*)(ws + OFF_B2R);
  bf16* pacc  = (bf16*)(ws + OFF_PACC);
  float* plv  = (float*)(ws + OFF_PL);
  bf16* wobf  = (bf16*)(ws + OFF_WOBF);
  bf16* xbt   = (bf16*)(ws + OFF_XBT);
  bf16* wall  = (bf16*)(ws + OFF_WALL);
  float* mprt = (float*)(ws + OFF_MPART);
  float* out  = (float*)d_out;

  hipLaunchKernelGGL(k_prep, dim3(512),  dim3(256), 0, stream, x, xbt, mprt);
  hipLaunchKernelGGL(k_pack, dim3(1024), dim3(256), 0, stream, mprt, gw1, gb1, gw2, gb2,
                     Wq, Wk, Wb1, Wb2, Wv, Wo, wall, wobf);
  hipLaunchKernelGGL(k_proj, dim3(512),  dim3(256), 0, stream, xbt, wall, qt, kt, b1r, b2r, vfg);
  hipLaunchKernelGGL(k_pool, dim3(NB * HW * KC / 256), dim3(256), 0, stream, b1r, b2r, wgb, bs1, bs2);
  hipLaunchKernelGGL(k_attn, dim3(1024), dim3(256), 0, stream, qt, kt, bs1, bs2, vfg, pacc, plv);
  hipLaunchKernelGGL(k_outc, dim3(512),  dim3(256), 0, stream, pacc, plv, wobf, bns, bnb, bnm, bnv, gam, x, out);
}